// Round 1
// baseline (6880.364 us; speedup 1.0000x reference)
//
#include <hip/hip_runtime.h>
#include <stdint.h>

typedef __attribute__((ext_vector_type(8))) short short8;
typedef __attribute__((ext_vector_type(4))) float float4v;

#define NB 64
#define NT 512
#define ND 512
#define NH 512

// ---- ws layout (bytes) ----
// P (bf16)  [T][B][4][H]            : off 0          size 134217728
// WU (bf16) [8 mats][n=512][k=512]  : off 134217728  size 4194304   (mats 0-3 = W, 4-7 = U)
// Hbuf(bf16)[2][B][H]               : off 138412032  size 131072
// cnt (u32) [4 bg][512 t]           : off 138543104  size 8192
#define OFF_WU   134217728UL
#define OFF_HBUF 138412032UL
#define OFF_CNT  138543104UL
#define WS_NEED  138551296UL

__device__ __forceinline__ unsigned short f2bf(float f) {
    union { float f; unsigned u; } v; v.f = f;
    unsigned r = v.u + 0x7fffu + ((v.u >> 16) & 1u);
    return (unsigned short)(r >> 16);
}
__device__ __forceinline__ float bf2f(unsigned short s) {
    union { unsigned u; float f; } v; v.u = ((unsigned)s) << 16;
    return v.f;
}
__device__ __forceinline__ float4v mfma16(short8 a, short8 b, float4v c) {
    return __builtin_amdgcn_mfma_f32_16x16x32_bf16(a, b, c, 0, 0, 0);
}
__device__ __forceinline__ float sigm(float x) { return 1.0f / (1.0f + __expf(-x)); }
__device__ __forceinline__ float tanh_fast(float x) { return 1.0f - 2.0f / (1.0f + __expf(2.0f * x)); }

struct Ptrs8 { const float* p[8]; };

// Transpose+convert all 8 weight matrices: dst[(mat*512+n)*512+k] = src_mat[k*512+n]  (bf16)
__global__ void convert_weights(Ptrs8 src, unsigned short* __restrict__ dst) {
    int tid = blockIdx.x * 256 + threadIdx.x;      // 2M threads
    int mat = tid >> 18;
    int rem = tid & 262143;
    int n = rem >> 9, k = rem & 511;
    dst[tid] = f2bf(src.p[mat][k * 512 + n]);
}

// P[t][b][g][h] = sum_d x[b][t][d] * W_g[d][h]   (bias folded in later)
// M = B*T = 32768 (m = b*512 + t), N = 2048 (n = g*512 + h), K = 512
__launch_bounds__(256, 1)
__global__ void proj_gemm(const float* __restrict__ x, const unsigned short* __restrict__ Wt,
                          unsigned short* __restrict__ P) {
    __shared__ unsigned short Alds[128 * 40];
    __shared__ unsigned short Blds[128 * 40];
    const int tid  = threadIdx.x;
    const int lane = tid & 63, wave = tid >> 6;
    const int wr = wave >> 1, wc = wave & 1;
    const int l15 = lane & 15, lq = lane >> 4;
    const int m0 = blockIdx.y * 128, n0 = blockIdx.x * 128;

    float4v acc[4][4];
    #pragma unroll
    for (int i = 0; i < 4; ++i)
        #pragma unroll
        for (int j = 0; j < 4; ++j) acc[i][j] = (float4v){0.f, 0.f, 0.f, 0.f};

    for (int k0 = 0; k0 < 512; k0 += 32) {
        #pragma unroll
        for (int i = 0; i < 2; ++i) {
            int c = tid + i * 256;              // 512 chunks of 8 elems
            int row = c >> 2, kc = c & 3;
            const float* s = x + (size_t)(m0 + row) * 512 + k0 + kc * 8;
            float4v u0 = *(const float4v*)s;
            float4v u1 = *(const float4v*)(s + 4);
            unsigned short t8[8] = { f2bf(u0.x), f2bf(u0.y), f2bf(u0.z), f2bf(u0.w),
                                     f2bf(u1.x), f2bf(u1.y), f2bf(u1.z), f2bf(u1.w) };
            *(short8*)&Alds[row * 40 + kc * 8] = *(short8*)t8;
            const unsigned short* sb = Wt + (size_t)(n0 + row) * 512 + k0 + kc * 8;
            *(short8*)&Blds[row * 40 + kc * 8] = *(const short8*)sb;
        }
        __syncthreads();
        short8 af[4], bfv[4];
        #pragma unroll
        for (int mi = 0; mi < 4; ++mi)
            af[mi] = *(short8*)&Alds[(wr * 64 + mi * 16 + l15) * 40 + lq * 8];
        #pragma unroll
        for (int ni = 0; ni < 4; ++ni)
            bfv[ni] = *(short8*)&Blds[(wc * 64 + ni * 16 + l15) * 40 + lq * 8];
        #pragma unroll
        for (int mi = 0; mi < 4; ++mi)
            #pragma unroll
            for (int ni = 0; ni < 4; ++ni)
                acc[mi][ni] = mfma16(af[mi], bfv[ni], acc[mi][ni]);
        __syncthreads();
    }
    #pragma unroll
    for (int mi = 0; mi < 4; ++mi)
        #pragma unroll
        for (int ni = 0; ni < 4; ++ni)
            #pragma unroll
            for (int r = 0; r < 4; ++r) {
                int m = m0 + wr * 64 + mi * 16 + lq * 4 + r;
                int n = n0 + wc * 64 + ni * 16 + l15;
                int tt = m & 511, bb = m >> 9, g = n >> 9, h = n & 511;
                P[(((size_t)tt * 64 + bb) * 4 + g) * 512 + h] = f2bf(acc[mi][ni][r]);
            }
}

// 64 blocks = 16 h-chunks (32 cols) x 4 batch-groups (16 rows). Wave = gate.
// U fragments live in registers for all 512 steps; h exchanged via global ping-pong + flags.
__launch_bounds__(256, 1)
__global__ void lstm_rec(const unsigned short* __restrict__ P,
                         const unsigned short* __restrict__ Ut,
                         unsigned short* __restrict__ Hbuf,
                         unsigned* __restrict__ cnt,
                         const float* __restrict__ bc, const float* __restrict__ bi,
                         const float* __restrict__ bff, const float* __restrict__ bo,
                         float* __restrict__ out) {
    const int tid  = threadIdx.x;
    const int lane = tid & 63, g = tid >> 6;
    const int l15 = lane & 15, lq = lane >> 4;
    const int hc = blockIdx.x >> 2, bg = blockIdx.x & 3;

    __shared__ float pre[4][16][33];
    __shared__ float cst[512];

    // preload U B-fragments: uf[tj][kt][j] = U_g[k = kt*32+lq*8+j][n = hc*32+tj*16+l15]
    short8 uf[2][16];
    #pragma unroll
    for (int tj = 0; tj < 2; ++tj) {
        const size_t nrow = (size_t)g * 512 + hc * 32 + tj * 16 + l15;
        #pragma unroll
        for (int kt = 0; kt < 16; ++kt)
            uf[tj][kt] = *(const short8*)&Ut[nrow * 512 + kt * 32 + lq * 8];
    }

    cst[tid] = 0.f; cst[tid + 256] = 0.f;
    __syncthreads();

    const unsigned cbase = bg * 512;
    #pragma unroll 1
    for (int t = 0; t < 512; ++t) {
        if (t > 0) {
            if (tid == 0) {
                while (atomicAdd(&cnt[cbase + t - 1], 0u) < 16u) __builtin_amdgcn_s_sleep(1);
            }
            __syncthreads();
            __threadfence();   // acquire: invalidate L1 before reading peers' h
        }
        float4v acc0 = (float4v){0.f, 0.f, 0.f, 0.f};
        float4v acc1 = (float4v){0.f, 0.f, 0.f, 0.f};
        if (t > 0) {
            const unsigned short* hsrc =
                Hbuf + ((t - 1) & 1) * (NB * NH) + (size_t)(bg * 16 + l15) * 512 + lq * 8;
            #pragma unroll
            for (int kt = 0; kt < 16; ++kt) {
                short8 a = *(const short8*)(hsrc + kt * 32);
                acc0 = mfma16(a, uf[0][kt], acc0);
                acc1 = mfma16(a, uf[1][kt], acc1);
            }
        }
        #pragma unroll
        for (int r = 0; r < 4; ++r) {
            pre[g][lq * 4 + r][l15]      = acc0[r];
            pre[g][lq * 4 + r][16 + l15] = acc1[r];
        }
        __syncthreads();
        #pragma unroll
        for (int rep = 0; rep < 2; ++rep) {
            int s = tid + rep * 256;
            int row = s >> 5, col = s & 31;
            int b = bg * 16 + row, h = hc * 32 + col;
            size_t pb = (((size_t)t * 64 + b) * 4) * 512 + h;
            float pa  = pre[0][row][col] + bf2f(P[pb])         + bc[h];
            float pi_ = pre[1][row][col] + bf2f(P[pb + 512])   + bi[h];
            float pf_ = pre[2][row][col] + bf2f(P[pb + 1024])  + bff[h];
            float po_ = pre[3][row][col] + bf2f(P[pb + 1536])  + bo[h];
            float av = tanh_fast(pa);
            float iv = sigm(pi_), fv = sigm(pf_), ov = sigm(po_);
            float cn = iv * av + fv * cst[s];
            cst[s] = cn;
            float hv = ov * tanh_fast(cn);
            out[((size_t)b * 512 + t) * 512 + h] = hv;
            Hbuf[(t & 1) * (NB * NH) + (size_t)b * 512 + h] = f2bf(hv);
        }
        __threadfence();       // release: drain h writes before flag
        __syncthreads();
        if (tid == 0) atomicAdd(&cnt[cbase + t], 1u);
    }
}

extern "C" void kernel_launch(void* const* d_in, const int* in_sizes, int n_in,
                              void* d_out, int out_size, void* d_ws, size_t ws_size,
                              hipStream_t stream) {
    (void)in_sizes; (void)n_in; (void)out_size;
    if (ws_size < WS_NEED) return;   // recognizable failure (output stays zero)

    const float* x = (const float*)d_in[0];
    Ptrs8 wp;
    for (int i = 0; i < 8; ++i) wp.p[i] = (const float*)d_in[1 + i];
    const float* bc = (const float*)d_in[9];
    const float* bi = (const float*)d_in[10];
    const float* bf = (const float*)d_in[11];
    const float* bo = (const float*)d_in[12];

    char* ws = (char*)d_ws;
    unsigned short* P    = (unsigned short*)ws;
    unsigned short* WU   = (unsigned short*)(ws + OFF_WU);
    unsigned short* Ut   = WU + 1048576;            // mats 4-7
    unsigned short* Hbuf = (unsigned short*)(ws + OFF_HBUF);
    unsigned*       cnt  = (unsigned*)(ws + OFF_CNT);

    hipMemsetAsync(cnt, 0, 8192, stream);
    convert_weights<<<8192, 256, 0, stream>>>(wp, WU);
    dim3 gg(16, 256);
    proj_gemm<<<gg, 256, 0, stream>>>(x, WU, P);
    lstm_rec<<<64, 256, 0, stream>>>(P, Ut, Hbuf, cnt, bc, bi, bf, bo, (float*)d_out);
}

// Round 3
// 4967.903 us; speedup vs baseline: 1.3850x; 1.3850x over previous
//
#include <hip/hip_runtime.h>
#include <stdint.h>

typedef __attribute__((ext_vector_type(8))) short short8;
typedef __attribute__((ext_vector_type(4))) float float4v;

#define NB 64
#define NT 512
#define ND 512
#define NH 512

// ---- ws layout (bytes) ----
// P (bf16)  [T][B][4][H]            : off 0          size 134217728
// WU (bf16) [8 mats][n=512][k=512]  : off 134217728  size 4194304   (mats 0-3 = W, 4-7 = U)
// Hbuf(bf16)[2][B][H]               : off 138412032  size 131072
// cnt (u32) [4 bg][512 t]           : off 138543104  size 8192
#define OFF_WU   134217728UL
#define OFF_HBUF 138412032UL
#define OFF_CNT  138543104UL
#define WS_NEED  138551296UL

__device__ __forceinline__ unsigned short f2bf(float f) {
    union { float f; unsigned u; } v; v.f = f;
    unsigned r = v.u + 0x7fffu + ((v.u >> 16) & 1u);
    return (unsigned short)(r >> 16);
}
__device__ __forceinline__ float bf2f(unsigned short s) {
    union { unsigned u; float f; } v; v.u = ((unsigned)s) << 16;
    return v.f;
}
__device__ __forceinline__ float4v mfma16(short8 a, short8 b, float4v c) {
    return __builtin_amdgcn_mfma_f32_16x16x32_bf16(a, b, c, 0, 0, 0);
}
__device__ __forceinline__ float sigm(float x) { return 1.0f / (1.0f + __expf(-x)); }
__device__ __forceinline__ float tanh_fast(float x) { return 1.0f - 2.0f / (1.0f + __expf(2.0f * x)); }

struct Ptrs8 { const float* p[8]; };

// Transpose+convert all 8 weight matrices: dst[(mat*512+n)*512+k] = src_mat[k*512+n]  (bf16)
__global__ void convert_weights(Ptrs8 src, unsigned short* __restrict__ dst) {
    int tid = blockIdx.x * 256 + threadIdx.x;      // 2M threads
    int mat = tid >> 18;
    int rem = tid & 262143;
    int n = rem >> 9, k = rem & 511;
    dst[tid] = f2bf(src.p[mat][k * 512 + n]);
}

// P[t][b][g][h] = sum_d x[b][t][d] * W_g[d][h]   (bias folded in later)
__launch_bounds__(256, 1)
__global__ void proj_gemm(const float* __restrict__ x, const unsigned short* __restrict__ Wt,
                          unsigned short* __restrict__ P) {
    __shared__ unsigned short Alds[128 * 40];
    __shared__ unsigned short Blds[128 * 40];
    const int tid  = threadIdx.x;
    const int lane = tid & 63, wave = tid >> 6;
    const int wr = wave >> 1, wc = wave & 1;
    const int l15 = lane & 15, lq = lane >> 4;
    const int m0 = blockIdx.y * 128, n0 = blockIdx.x * 128;

    float4v acc[4][4];
    #pragma unroll
    for (int i = 0; i < 4; ++i)
        #pragma unroll
        for (int j = 0; j < 4; ++j) acc[i][j] = (float4v){0.f, 0.f, 0.f, 0.f};

    for (int k0 = 0; k0 < 512; k0 += 32) {
        #pragma unroll
        for (int i = 0; i < 2; ++i) {
            int c = tid + i * 256;
            int row = c >> 2, kc = c & 3;
            const float* s = x + (size_t)(m0 + row) * 512 + k0 + kc * 8;
            float4v u0 = *(const float4v*)s;
            float4v u1 = *(const float4v*)(s + 4);
            unsigned short t8[8] = { f2bf(u0.x), f2bf(u0.y), f2bf(u0.z), f2bf(u0.w),
                                     f2bf(u1.x), f2bf(u1.y), f2bf(u1.z), f2bf(u1.w) };
            *(short8*)&Alds[row * 40 + kc * 8] = *(short8*)t8;
            const unsigned short* sb = Wt + (size_t)(n0 + row) * 512 + k0 + kc * 8;
            *(short8*)&Blds[row * 40 + kc * 8] = *(const short8*)sb;
        }
        __syncthreads();
        short8 af[4], bfv[4];
        #pragma unroll
        for (int mi = 0; mi < 4; ++mi)
            af[mi] = *(short8*)&Alds[(wr * 64 + mi * 16 + l15) * 40 + lq * 8];
        #pragma unroll
        for (int ni = 0; ni < 4; ++ni)
            bfv[ni] = *(short8*)&Blds[(wc * 64 + ni * 16 + l15) * 40 + lq * 8];
        #pragma unroll
        for (int mi = 0; mi < 4; ++mi)
            #pragma unroll
            for (int ni = 0; ni < 4; ++ni)
                acc[mi][ni] = mfma16(af[mi], bfv[ni], acc[mi][ni]);
        __syncthreads();
    }
    #pragma unroll
    for (int mi = 0; mi < 4; ++mi)
        #pragma unroll
        for (int ni = 0; ni < 4; ++ni)
            #pragma unroll
            for (int r = 0; r < 4; ++r) {
                int m = m0 + wr * 64 + mi * 16 + lq * 4 + r;
                int n = n0 + wc * 64 + ni * 16 + l15;
                int tt = m & 511, bb = m >> 9, gg = n >> 9, hh = n & 511;
                P[(((size_t)tt * 64 + bb) * 4 + gg) * 512 + hh] = f2bf(acc[mi][ni][r]);
            }
}

// 32 blocks = 8 h-chunks (64 cols) x 4 batch-groups (16 rows). Wave = gate.
// U fragments live in registers (unified VGPR/AGPR file) for all 512 steps.
// ALL cross-block traffic (h data + flags) uses RMW atomics — executed at the
// device coherence point — so no __threadfence (full-L2 wb/inv, the R1 killer)
// and no plain-store visibility races (the R2 killer).
__launch_bounds__(256, 1)
__global__ void lstm_rec(const unsigned short* __restrict__ P,
                         const unsigned short* __restrict__ Ut,
                         unsigned short* __restrict__ Hbuf,
                         unsigned* __restrict__ cnt,
                         const float* __restrict__ bc, const float* __restrict__ bi,
                         const float* __restrict__ bff, const float* __restrict__ bo,
                         float* __restrict__ out) {
    const int tid  = threadIdx.x;
    const int lane = tid & 63, g = tid >> 6;
    const int l15 = lane & 15, lq = lane >> 4;
    const int hc = blockIdx.x >> 2, bg = blockIdx.x & 3;

    __shared__ float pre[2][4][16][65];

    // preload U B-fragments for 64 cols: uf[tj][kt][j] = U_g[k=kt*32+lq*8+j][n=hc*64+tj*16+l15]
    short8 uf[4][16];
    #pragma unroll
    for (int tj = 0; tj < 4; ++tj) {
        const size_t nrow = (size_t)g * 512 + hc * 64 + tj * 16 + l15;
        #pragma unroll
        for (int kt = 0; kt < 16; ++kt)
            uf[tj][kt] = *(const short8*)&Ut[nrow * 512 + kt * 32 + lq * 8];
    }

    // per-thread gate-stage mapping: 2 reps, each owns a pair of adjacent cols
    int rowi[2], hbase[2], bidx[2];
    float bias[2][4][2];
    float creg[2][2] = {{0.f, 0.f}, {0.f, 0.f}};
    #pragma unroll
    for (int rep = 0; rep < 2; ++rep) {
        int pair = tid + rep * 256;
        rowi[rep] = pair >> 5;
        int colp = pair & 31;
        hbase[rep] = hc * 64 + colp * 2;
        bidx[rep] = bg * 16 + rowi[rep];
        int h = hbase[rep];
        bias[rep][0][0] = bc[h];  bias[rep][0][1] = bc[h + 1];
        bias[rep][1][0] = bi[h];  bias[rep][1][1] = bi[h + 1];
        bias[rep][2][0] = bff[h]; bias[rep][2][1] = bff[h + 1];
        bias[rep][3][0] = bo[h];  bias[rep][3][1] = bo[h + 1];
    }
    const unsigned* Pp[2][4];
    float* outp[2];
    #pragma unroll
    for (int rep = 0; rep < 2; ++rep) {
        #pragma unroll
        for (int g2 = 0; g2 < 4; ++g2)
            Pp[rep][g2] = (const unsigned*)(P + (((size_t)bidx[rep] * 4 + g2) * 512 + hbase[rep]));
        outp[rep] = out + (size_t)bidx[rep] * 512 * 512 + hbase[rep];
    }
    unsigned* Hb32 = (unsigned*)Hbuf;
    const unsigned cbase = bg * 512;

    #pragma unroll 1
    for (int t = 0; t < 512; ++t) {
        // issue P loads early (plain loads of constant data) so they fly during the poll
        unsigned pv[2][4];
        #pragma unroll
        for (int rep = 0; rep < 2; ++rep)
            #pragma unroll
            for (int g2 = 0; g2 < 4; ++g2) {
                pv[rep][g2] = *Pp[rep][g2];
                Pp[rep][g2] += 65536;          // t stride: 64*4*512 bf16 = 65536 u32
            }

        float4v acc[4];
        #pragma unroll
        for (int tj = 0; tj < 4; ++tj) acc[tj] = (float4v){0.f, 0.f, 0.f, 0.f};

        if (t > 0) {
            if (lane == 0) {   // whole wave blocks here via exec-mask divergence
                while (atomicAdd(&cnt[cbase + t - 1], 0u) < 8u)
                    __builtin_amdgcn_s_sleep(1);
            }
            // h gather: RMW reads — performed at the coherence point, always fresh
            unsigned* hp32 = Hb32 + ((t - 1) & 1) * 16384
                                  + (size_t)(bg * 16 + l15) * 256 + lq * 4;
            unsigned hv32[16][4];
            #pragma unroll
            for (int kt = 0; kt < 16; ++kt)
                #pragma unroll
                for (int i = 0; i < 4; ++i)
                    hv32[kt][i] = atomicAdd(hp32 + kt * 16 + i, 0u);
            #pragma unroll
            for (int kt = 0; kt < 16; ++kt) {
                union { unsigned q[4]; short8 s; } u;
                u.q[0] = hv32[kt][0]; u.q[1] = hv32[kt][1];
                u.q[2] = hv32[kt][2]; u.q[3] = hv32[kt][3];
                #pragma unroll
                for (int tj = 0; tj < 4; ++tj)
                    acc[tj] = mfma16(u.s, uf[tj][kt], acc[tj]);
            }
        }
        const int buf = t & 1;
        #pragma unroll
        for (int tj = 0; tj < 4; ++tj)
            #pragma unroll
            for (int r = 0; r < 4; ++r)
                pre[buf][g][lq * 4 + r][tj * 16 + l15] = acc[tj][r];
        __syncthreads();

        #pragma unroll
        for (int rep = 0; rep < 2; ++rep) {
            const int row = rowi[rep];
            const int col0 = hbase[rep] & 63;       // col within block slice
            float hv2[2];
            #pragma unroll
            for (int j = 0; j < 2; ++j) {
                unsigned p0 = pv[rep][0], p1 = pv[rep][1], p2 = pv[rep][2], p3 = pv[rep][3];
                float pa  = pre[buf][0][row][col0 + j] + bf2f((unsigned short)(j ? (p0 >> 16) : (p0 & 0xffff))) + bias[rep][0][j];
                float pi_ = pre[buf][1][row][col0 + j] + bf2f((unsigned short)(j ? (p1 >> 16) : (p1 & 0xffff))) + bias[rep][1][j];
                float pf_ = pre[buf][2][row][col0 + j] + bf2f((unsigned short)(j ? (p2 >> 16) : (p2 & 0xffff))) + bias[rep][2][j];
                float po_ = pre[buf][3][row][col0 + j] + bf2f((unsigned short)(j ? (p3 >> 16) : (p3 & 0xffff))) + bias[rep][3][j];
                float av = tanh_fast(pa);
                float iv = sigm(pi_), fv = sigm(pf_), ov = sigm(po_);
                float cn = iv * av + fv * creg[rep][j];
                creg[rep][j] = cn;
                hv2[j] = ov * tanh_fast(cn);
            }
            // out: normal cached store (flushed at kernel end)
            *(float2*)(outp[rep] + (size_t)t * 512) = make_float2(hv2[0], hv2[1]);
            // h: RMW store (atomicExch) — executed at the coherence point
            unsigned packed = ((unsigned)f2bf(hv2[1]) << 16) | (unsigned)f2bf(hv2[0]);
            atomicExch(&Hb32[buf * 16384 + bidx[rep] * 256 + (hbase[rep] >> 1)], packed);
        }

        // drain this wave's exchs (performed at coherence point once vmcnt retires),
        // then block barrier so tid0's flag-add orders after ALL waves' exchs
        asm volatile("s_waitcnt vmcnt(0)" ::: "memory");
        __syncthreads();
        if (tid == 0)
            atomicAdd(&cnt[cbase + t], 1u);
    }
}

extern "C" void kernel_launch(void* const* d_in, const int* in_sizes, int n_in,
                              void* d_out, int out_size, void* d_ws, size_t ws_size,
                              hipStream_t stream) {
    (void)in_sizes; (void)n_in; (void)out_size;
    if (ws_size < WS_NEED) return;

    const float* x = (const float*)d_in[0];
    Ptrs8 wp;
    for (int i = 0; i < 8; ++i) wp.p[i] = (const float*)d_in[1 + i];
    const float* bc = (const float*)d_in[9];
    const float* bi = (const float*)d_in[10];
    const float* bf = (const float*)d_in[11];
    const float* bo = (const float*)d_in[12];

    char* ws = (char*)d_ws;
    unsigned short* P    = (unsigned short*)ws;
    unsigned short* WU   = (unsigned short*)(ws + OFF_WU);
    unsigned short* Ut   = WU + 1048576;            // mats 4-7
    unsigned short* Hbuf = (unsigned short*)(ws + OFF_HBUF);
    unsigned*       cnt  = (unsigned*)(ws + OFF_CNT);

    hipMemsetAsync(cnt, 0, 8192, stream);
    convert_weights<<<8192, 256, 0, stream>>>(wp, WU);
    dim3 gg(16, 256);
    proj_gemm<<<gg, 256, 0, stream>>>(x, WU, P);
    lstm_rec<<<32, 256, 0, stream>>>(P, Ut, Hbuf, cnt, bc, bi, bf, bo, (float*)d_out);
}

// Round 4
// 3623.461 us; speedup vs baseline: 1.8988x; 1.3710x over previous
//
#include <hip/hip_runtime.h>
#include <stdint.h>

typedef __attribute__((ext_vector_type(8))) short short8;
typedef __attribute__((ext_vector_type(4))) float float4v;

#define NB 64
#define NT 512
#define ND 512
#define NH 512

// ---- ws layout (bytes) ----
// P (bf16)  [T][B][4][H]            : off 0          size 134217728
//   NOTE: P[t-1]'s per-bg 64KB chunk doubles as the tagged h[t] slot (front
//   32KB) once every same-bg block has prefetched P[t-1] — proven dead by tag
//   causality (block at step t saw tags t-1 => peers passed P[t-1] prefetch).
// WU (bf16) [8 mats][n=512][k=512]  : off 134217728  size 4194304   (mats 0-3 = W, 4-7 = U)
// Hspare (tagged u64 h[0] slot)     : off 138412032  size 131072
#define OFF_WU     134217728UL
#define OFF_HSPARE 138412032UL
#define WS_NEED    138551296UL

__device__ __forceinline__ unsigned short f2bf(float f) {
    union { float f; unsigned u; } v; v.f = f;
    unsigned r = v.u + 0x7fffu + ((v.u >> 16) & 1u);
    return (unsigned short)(r >> 16);
}
__device__ __forceinline__ float bf2f(unsigned short s) {
    union { unsigned u; float f; } v; v.u = ((unsigned)s) << 16;
    return v.f;
}
__device__ __forceinline__ float4v mfma16(short8 a, short8 b, float4v c) {
    return __builtin_amdgcn_mfma_f32_16x16x32_bf16(a, b, c, 0, 0, 0);
}
__device__ __forceinline__ float sigm(float x) { return 1.0f / (1.0f + __expf(-x)); }
__device__ __forceinline__ float tanh_fast(float x) { return 1.0f - 2.0f / (1.0f + __expf(2.0f * x)); }

struct Ptrs8 { const float* p[8]; };

// Transpose+convert all 8 weight matrices: dst[(mat*512+n)*512+k] = src_mat[k*512+n]  (bf16)
__global__ void convert_weights(Ptrs8 src, unsigned short* __restrict__ dst) {
    int tid = blockIdx.x * 256 + threadIdx.x;      // 2M threads
    int mat = tid >> 18;
    int rem = tid & 262143;
    int n = rem >> 9, k = rem & 511;
    dst[tid] = f2bf(src.p[mat][k * 512 + n]);
}

// P[t][b][g][h] = sum_d x[b][t][d] * W_g[d][h]   (bias folded in later)
__launch_bounds__(256, 1)
__global__ void proj_gemm(const float* __restrict__ x, const unsigned short* __restrict__ Wt,
                          unsigned short* __restrict__ P) {
    __shared__ unsigned short Alds[128 * 40];
    __shared__ unsigned short Blds[128 * 40];
    const int tid  = threadIdx.x;
    const int lane = tid & 63, wave = tid >> 6;
    const int wr = wave >> 1, wc = wave & 1;
    const int l15 = lane & 15, lq = lane >> 4;
    const int m0 = blockIdx.y * 128, n0 = blockIdx.x * 128;

    float4v acc[4][4];
    #pragma unroll
    for (int i = 0; i < 4; ++i)
        #pragma unroll
        for (int j = 0; j < 4; ++j) acc[i][j] = (float4v){0.f, 0.f, 0.f, 0.f};

    for (int k0 = 0; k0 < 512; k0 += 32) {
        #pragma unroll
        for (int i = 0; i < 2; ++i) {
            int c = tid + i * 256;
            int row = c >> 2, kc = c & 3;
            const float* s = x + (size_t)(m0 + row) * 512 + k0 + kc * 8;
            float4v u0 = *(const float4v*)s;
            float4v u1 = *(const float4v*)(s + 4);
            unsigned short t8[8] = { f2bf(u0.x), f2bf(u0.y), f2bf(u0.z), f2bf(u0.w),
                                     f2bf(u1.x), f2bf(u1.y), f2bf(u1.z), f2bf(u1.w) };
            *(short8*)&Alds[row * 40 + kc * 8] = *(short8*)t8;
            const unsigned short* sb = Wt + (size_t)(n0 + row) * 512 + k0 + kc * 8;
            *(short8*)&Blds[row * 40 + kc * 8] = *(const short8*)sb;
        }
        __syncthreads();
        short8 af[4], bfv[4];
        #pragma unroll
        for (int mi = 0; mi < 4; ++mi)
            af[mi] = *(short8*)&Alds[(wr * 64 + mi * 16 + l15) * 40 + lq * 8];
        #pragma unroll
        for (int ni = 0; ni < 4; ++ni)
            bfv[ni] = *(short8*)&Blds[(wc * 64 + ni * 16 + l15) * 40 + lq * 8];
        #pragma unroll
        for (int mi = 0; mi < 4; ++mi)
            #pragma unroll
            for (int ni = 0; ni < 4; ++ni)
                acc[mi][ni] = mfma16(af[mi], bfv[ni], acc[mi][ni]);
        __syncthreads();
    }
    #pragma unroll
    for (int mi = 0; mi < 4; ++mi)
        #pragma unroll
        for (int ni = 0; ni < 4; ++ni)
            #pragma unroll
            for (int r = 0; r < 4; ++r) {
                int m = m0 + wr * 64 + mi * 16 + lq * 4 + r;
                int n = n0 + wc * 64 + ni * 16 + l15;
                int tt = m & 511, bb = m >> 9, gg = n >> 9, hh = n & 511;
                P[(((size_t)tt * 64 + bb) * 4 + gg) * 512 + hh] = f2bf(acc[mi][ni][r]);
            }
}

// 32 blocks = 8 h-chunks (64 cols) x 4 batch-groups (16 rows). Wave = gate.
// U fragments live in registers for all 512 steps. h exchange: single-word
// tagged u64 {tag=t, 2xbf16} via atomicExch; consumers poll the data itself
// with u64 RMW reads (tag+data atomic in one word => no flag/data ordering
// hazard, no fences, no flags). Gather is done once per block and shared
// through LDS (4096 u64 RMW/block/step vs R3's 16384 u32).
__launch_bounds__(256, 1)
__global__ void lstm_rec(unsigned short* __restrict__ P,
                         const unsigned short* __restrict__ Ut,
                         unsigned long long* __restrict__ Hspare,
                         const float* __restrict__ bc, const float* __restrict__ bi,
                         const float* __restrict__ bff, const float* __restrict__ bo,
                         float* __restrict__ out) {
    const int tid  = threadIdx.x;
    const int lane = tid & 63, g = tid >> 6;
    const int l15 = lane & 15, lq = lane >> 4;
    const int hc = blockIdx.x >> 2, bg = blockIdx.x & 3;

    __shared__ unsigned hsh[16 * 260];        // [row][pair], stride 260 (2-way banks = free)
    __shared__ float pre[4][16][65];

    unsigned long long* Pov = (unsigned long long*)P;

    // preload U B-fragments for 64 cols: uf[tj][kt][j] = U_g[k=kt*32+lq*8+j][n=hc*64+tj*16+l15]
    short8 uf[4][16];
    #pragma unroll
    for (int tj = 0; tj < 4; ++tj) {
        const size_t nrow = (size_t)g * 512 + hc * 64 + tj * 16 + l15;
        #pragma unroll
        for (int kt = 0; kt < 16; ++kt)
            uf[tj][kt] = *(const short8*)&Ut[nrow * 512 + kt * 32 + lq * 8];
    }

    // per-thread gate-stage mapping: 2 reps, each owns a pair of adjacent cols
    int rowi[2], hbase[2], bidx[2];
    float bias[2][4][2];
    float creg[2][2] = {{0.f, 0.f}, {0.f, 0.f}};
    #pragma unroll
    for (int rep = 0; rep < 2; ++rep) {
        int pair = tid + rep * 256;
        rowi[rep] = pair >> 5;
        int colp = pair & 31;
        hbase[rep] = hc * 64 + colp * 2;
        bidx[rep] = bg * 16 + rowi[rep];
        int h = hbase[rep];
        bias[rep][0][0] = bc[h];  bias[rep][0][1] = bc[h + 1];
        bias[rep][1][0] = bi[h];  bias[rep][1][1] = bi[h + 1];
        bias[rep][2][0] = bff[h]; bias[rep][2][1] = bff[h + 1];
        bias[rep][3][0] = bo[h];  bias[rep][3][1] = bo[h + 1];
    }
    const unsigned* Pp[2][4];
    float* outp[2];
    #pragma unroll
    for (int rep = 0; rep < 2; ++rep) {
        #pragma unroll
        for (int g2 = 0; g2 < 4; ++g2)
            Pp[rep][g2] = (const unsigned*)(P + (((size_t)bidx[rep] * 4 + g2) * 512 + hbase[rep]));
        outp[rep] = out + (size_t)bidx[rep] * 512 * 512 + hbase[rep];
    }

    #pragma unroll 1
    for (int t = 0; t < 512; ++t) {
        // P prefetch (plain cached loads; value captured before any peer can
        // overwrite this region — peer at t+1 implies we already wrote h[t],
        // which happens after these are consumed)
        unsigned pv[2][4];
        #pragma unroll
        for (int rep = 0; rep < 2; ++rep)
            #pragma unroll
            for (int g2 = 0; g2 < 4; ++g2) {
                pv[rep][g2] = *Pp[rep][g2];
                Pp[rep][g2] += 65536;          // t stride: 64*4*512 bf16 = 65536 u32
            }

        float4v acc[4];
        #pragma unroll
        for (int tj = 0; tj < 4; ++tj) acc[tj] = (float4v){0.f, 0.f, 0.f, 0.f};

        if (t > 0) {
            // gather slot(t-1): tagged u64, poll until tag == t-1
            unsigned long long* slot = (t == 1)
                ? Hspare + (size_t)(bg * 16) * 256
                : Pov + ((size_t)(t - 2) * 64 + bg * 16) * 512;
            const unsigned want = (unsigned)(t - 1);
            unsigned pend = 0xffffu;
            while (pend) {
                #pragma unroll
                for (int k = 0; k < 16; ++k) {
                    if (pend & (1u << k)) {
                        unsigned long long v = atomicAdd(&slot[k * 256 + tid], 0ull);
                        if ((unsigned)(v >> 32) == want) {
                            hsh[k * 260 + tid] = (unsigned)v;
                            pend &= ~(1u << k);
                        }
                    }
                }
            }
        }
        __syncthreads();   // hsh ready (and pre free for rewrite)

        if (t > 0) {
            #pragma unroll
            for (int kt = 0; kt < 16; ++kt) {
                short8 a = *(short8*)&hsh[l15 * 260 + kt * 16 + lq * 4];
                #pragma unroll
                for (int tj = 0; tj < 4; ++tj)
                    acc[tj] = mfma16(a, uf[tj][kt], acc[tj]);
            }
        }
        #pragma unroll
        for (int tj = 0; tj < 4; ++tj)
            #pragma unroll
            for (int r = 0; r < 4; ++r)
                pre[g][lq * 4 + r][tj * 16 + l15] = acc[tj][r];
        __syncthreads();   // pre ready (and hsh free for next gather)

        #pragma unroll
        for (int rep = 0; rep < 2; ++rep) {
            const int row = rowi[rep];
            const int col0 = hbase[rep] & 63;
            float hv2[2];
            #pragma unroll
            for (int j = 0; j < 2; ++j) {
                unsigned p0 = pv[rep][0], p1 = pv[rep][1], p2 = pv[rep][2], p3 = pv[rep][3];
                float pa  = pre[0][row][col0 + j] + bf2f((unsigned short)(j ? (p0 >> 16) : (p0 & 0xffff))) + bias[rep][0][j];
                float pi_ = pre[1][row][col0 + j] + bf2f((unsigned short)(j ? (p1 >> 16) : (p1 & 0xffff))) + bias[rep][1][j];
                float pf_ = pre[2][row][col0 + j] + bf2f((unsigned short)(j ? (p2 >> 16) : (p2 & 0xffff))) + bias[rep][2][j];
                float po_ = pre[3][row][col0 + j] + bf2f((unsigned short)(j ? (p3 >> 16) : (p3 & 0xffff))) + bias[rep][3][j];
                float av = tanh_fast(pa);
                float iv = sigm(pi_), fv = sigm(pf_), ov = sigm(po_);
                float cn = iv * av + fv * creg[rep][j];
                creg[rep][j] = cn;
                hv2[j] = ov * tanh_fast(cn);
            }
            // out: normal cached store (flushed at kernel end)
            *(float2*)(outp[rep] + (size_t)t * 512) = make_float2(hv2[0], hv2[1]);
            // h: single-word tagged exch — tag and data atomic together
            unsigned packed = ((unsigned)f2bf(hv2[1]) << 16) | (unsigned)f2bf(hv2[0]);
            unsigned long long val = ((unsigned long long)(unsigned)t << 32) | packed;
            unsigned long long* dst = (t == 0)
                ? Hspare + (size_t)bidx[rep] * 256 + (hbase[rep] >> 1)
                : Pov + ((size_t)(t - 1) * 64 + bg * 16) * 512
                      + (size_t)rowi[rep] * 256 + (hbase[rep] >> 1);
            atomicExch(dst, val);
        }
        // no fence, no flag: consumers poll the tagged words themselves
    }
}

extern "C" void kernel_launch(void* const* d_in, const int* in_sizes, int n_in,
                              void* d_out, int out_size, void* d_ws, size_t ws_size,
                              hipStream_t stream) {
    (void)in_sizes; (void)n_in; (void)out_size;
    if (ws_size < WS_NEED) return;

    const float* x = (const float*)d_in[0];
    Ptrs8 wp;
    for (int i = 0; i < 8; ++i) wp.p[i] = (const float*)d_in[1 + i];
    const float* bc = (const float*)d_in[9];
    const float* bi = (const float*)d_in[10];
    const float* bf = (const float*)d_in[11];
    const float* bo = (const float*)d_in[12];

    char* ws = (char*)d_ws;
    unsigned short* P      = (unsigned short*)ws;
    unsigned short* WU     = (unsigned short*)(ws + OFF_WU);
    unsigned short* Ut     = WU + 1048576;            // mats 4-7
    unsigned long long* Hs = (unsigned long long*)(ws + OFF_HSPARE);

    convert_weights<<<8192, 256, 0, stream>>>(wp, WU);
    dim3 gg(16, 256);
    proj_gemm<<<gg, 256, 0, stream>>>(x, WU, P);
    lstm_rec<<<32, 256, 0, stream>>>(P, Ut, Hs, bc, bi, bf, bo, (float*)d_out);
}